// Round 2
// baseline (1835.077 us; speedup 1.0000x reference)
//
#include <hip/hip_runtime.h>
#include <hip/hip_bf16.h>
#include <stdint.h>
#include <math.h>

#define DEVINL static __device__ __forceinline__

static constexpr int BB = 8, NN = 4096, SS = 1024, KK = 24, CC = 64;
static constexpr int INCH = 131, OUTCH = 128;

// ---------------------------------------------------------------------------
// prep 1: xyz -> SoA f32 + per-point ||p||^2 (exact np op order, no FMA fusion)
// ---------------------------------------------------------------------------
__global__ __launch_bounds__(256) void k_prep_xyz(
    const float* __restrict__ xyz,
    float* __restrict__ xs, float* __restrict__ ys,
    float* __restrict__ zs, float* __restrict__ sb) {
  int e = blockIdx.x * 256 + threadIdx.x;
  if (e >= BB * NN) return;
  float x = xyz[e * 3 + 0];
  float y = xyz[e * 3 + 1];
  float z = xyz[e * 3 + 2];
  xs[e] = x; ys[e] = y; zs[e] = z;
  sb[e] = __fadd_rn(__fadd_rn(__fmul_rn(x, x), __fmul_rn(y, y)), __fmul_rn(z, z));
}

// ---------------------------------------------------------------------------
// prep 2: transpose all conv weights to [ci][co] f32; fold conv-bias + BN into
// per-channel scale/bias.
// wt_sq layer order: 0 pre_w1[0], 1 pre_w2[0], 2 pre_w1[1], 3 pre_w2[1],
//                    4 pos_w1[0], 5 pos_w2[0], 6 pos_w1[1], 7 pos_w2[1]
// bnsb layer order:  0 transfer, 1..4 pre (1a,1b,2a,2b), 5..8 pos (1a,1b,2a,2b)
// ---------------------------------------------------------------------------
__global__ __launch_bounds__(256) void k_prep_w(
    const float* __restrict__ tw,
    const float* __restrict__ pw1, const float* __restrict__ pw2,
    const float* __restrict__ qw1, const float* __restrict__ qw2,
    const float* __restrict__ tb,  const float* __restrict__ tbn,
    const float* __restrict__ pb1, const float* __restrict__ pbn1,
    const float* __restrict__ pb2, const float* __restrict__ pbn2,
    const float* __restrict__ qb1, const float* __restrict__ qbn1,
    const float* __restrict__ qb2, const float* __restrict__ qbn2,
    float* __restrict__ wt_tr, float* __restrict__ wt_sq, float* __restrict__ bnsb) {
  int e = blockIdx.x * 256 + threadIdx.x;
  const int NTR = INCH * 128;          // 16768
  const int NSQ = 8 * 128 * 128;       // 131072
  if (e < NTR) {
    int ci = e >> 7, co = e & 127;
    wt_tr[e] = tw[co * INCH + ci];
  } else if (e < NTR + NSQ) {
    int r = e - NTR;
    int layer = r >> 14, m = r & 16383;
    int ci = m >> 7, co = m & 127;
    const float* src;
    switch (layer) {
      case 0: src = pw1;         break;
      case 1: src = pw2;         break;
      case 2: src = pw1 + 16384; break;
      case 3: src = pw2 + 16384; break;
      case 4: src = qw1;         break;
      case 5: src = qw2;         break;
      case 6: src = qw1 + 16384; break;
      default: src = qw2 + 16384; break;
    }
    wt_sq[layer * 16384 + ci * 128 + co] = src[co * 128 + ci];
  } else if (e < NTR + NSQ + 9 * 128) {
    int r = e - (NTR + NSQ);
    int L = r >> 7, co = r & 127;
    const float *bn, *bc;
    switch (L) {
      case 0: bn = tbn;        bc = tb;        break;
      case 1: bn = pbn1;       bc = pb1;       break;
      case 2: bn = pbn2;       bc = pb2;       break;
      case 3: bn = pbn1 + 512; bc = pb1 + 128; break;
      case 4: bn = pbn2 + 512; bc = pb2 + 128; break;
      case 5: bn = qbn1;       bc = qb1;       break;
      case 6: bn = qbn2;       bc = qb2;       break;
      case 7: bn = qbn1 + 512; bc = qb1 + 128; break;
      default: bn = qbn2 + 512; bc = qb2 + 128; break;
    }
    float g  = bn[co];
    float be = bn[128 + co];
    float mu = bn[256 + co];
    float va = bn[384 + co];
    float bcv = bc[co];
    float sc = g / sqrtf(va + 1e-5f);
    float bi = (bcv - mu) * sc + be;
    bnsb[L * 256 + co] = sc;
    bnsb[L * 256 + 128 + co] = bi;
  }
}

// ---------------------------------------------------------------------------
// FPS: one block per batch; 512 threads x 8 points each; single barrier per
// iteration (double-buffered per-wave partials, redundant final reduce).
// Key = (dist_bits<<32) | (4095-n): max-reduce => argmax with first-index ties
// (matches np.argmax). Also gathers new_xyz / sa / new_points as a tail.
// ---------------------------------------------------------------------------
__global__ __launch_bounds__(512, 2) void k_fps(
    const float* __restrict__ xs, const float* __restrict__ ys,
    const float* __restrict__ zs, const float* __restrict__ sb,
    const float* __restrict__ points,
    int* __restrict__ fps_idx, float* __restrict__ nxyz,
    float* __restrict__ sa, float* __restrict__ newp) {
  __shared__ float lx[NN], ly[NN], lz[NN];
  __shared__ unsigned long long part[2][8];
  __shared__ int fpsl[SS];
  const int b = blockIdx.x, t = threadIdx.x;
  const int wid = t >> 6, lane = t & 63;
  const float* bx = xs + b * NN;
  const float* by = ys + b * NN;
  const float* bz = zs + b * NN;
  for (int e = t; e < NN; e += 512) { lx[e] = bx[e]; ly[e] = by[e]; lz[e] = bz[e]; }
  float d[8];
#pragma unroll
  for (int j = 0; j < 8; j++) d[j] = 1e10f;
  __syncthreads();
  float px = lx[0], py = ly[0], pz = lz[0];
  if (t == 0) { fpsl[0] = 0; fps_idx[b * SS] = 0; }
#pragma unroll 1
  for (int i = 1; i < SS; i++) {
    unsigned long long bk = 0ull;
#pragma unroll
    for (int j = 0; j < 8; j++) {
      int n = j * 512 + t;
      float dx = __fsub_rn(lx[n], px);
      float dy = __fsub_rn(ly[n], py);
      float dz = __fsub_rn(lz[n], pz);
      float dd = __fadd_rn(__fadd_rn(__fmul_rn(dx, dx), __fmul_rn(dy, dy)), __fmul_rn(dz, dz));
      float nd = fminf(d[j], dd);
      d[j] = nd;
      unsigned long long key =
          ((unsigned long long)__float_as_uint(nd) << 32) | (unsigned)(NN - 1 - n);
      bk = key > bk ? key : bk;
    }
#pragma unroll
    for (int m = 1; m < 64; m <<= 1) {
      unsigned long long o = __shfl_xor(bk, m);
      bk = o > bk ? o : bk;
    }
    if (lane == 0) part[i & 1][wid] = bk;
    __syncthreads();
    unsigned long long g = part[i & 1][0];
#pragma unroll
    for (int w = 1; w < 8; w++) {
      unsigned long long o = part[i & 1][w];
      g = o > g ? o : g;
    }
    int n = (NN - 1) - (int)(unsigned)g;
    px = lx[n]; py = ly[n]; pz = lz[n];
    if (t == 0) { fpsl[i] = n; fps_idx[b * SS + i] = n; }
  }
  __syncthreads();
  for (int s = t; s < SS; s += 512) {
    int row = fpsl[s];
    nxyz[(b * SS + s) * 3 + 0] = lx[row];
    nxyz[(b * SS + s) * 3 + 1] = ly[row];
    nxyz[(b * SS + s) * 3 + 2] = lz[row];
    sa[b * SS + s] = sb[b * NN + row];
  }
  for (int e = t; e < SS * CC; e += 512) {
    int s = e >> 6, c = e & 63;
    int row = fpsl[s];
    newp[(b * SS + s) * CC + c] = points[(b * NN + row) * CC + c];
  }
}

// ---------------------------------------------------------------------------
// KNN + std partial sums: one wave per query. 64 dist keys in registers,
// 24 rounds of wave-wide argmin extraction on (key,n) u64 (exact stable top-k
// set). Distances use the reference's expanded form with exact f32 op order.
// Then each wave accumulates diff sums (f64) for the batch-wide std.
// ---------------------------------------------------------------------------
__global__ __launch_bounds__(256, 2) void k_knn(
    const float* __restrict__ xs, const float* __restrict__ ys,
    const float* __restrict__ zs,
    const float* __restrict__ nxyz, const float* __restrict__ sa,
    const float* __restrict__ points, const float* __restrict__ newp,
    int* __restrict__ knn, double* __restrict__ spart) {
  __shared__ float lx[NN], ly[NN], lz[NN];
  __shared__ int selk[4][KK];
  const int blk = blockIdx.x, t = threadIdx.x, wid = t >> 6, lane = t & 63;
  const int b = blk >> 8;  // 256 blocks per batch
  for (int e = t; e < NN; e += 256) {
    lx[e] = xs[b * NN + e]; ly[e] = ys[b * NN + e]; lz[e] = zs[b * NN + e];
  }
  __syncthreads();
  const int q = blk * 4 + wid;
  float qx = nxyz[q * 3 + 0], qy = nxyz[q * 3 + 1], qz = nxyz[q * 3 + 2];
  float qa = sa[q];
  unsigned keys[64];
#pragma unroll
  for (int j = 0; j < 64; j++) {
    int n = j * 64 + lane;
    float x = lx[n], y = ly[n], z = lz[n];
    float sbn = __fadd_rn(__fadd_rn(__fmul_rn(x, x), __fmul_rn(y, y)), __fmul_rn(z, z));
    float dot = __fadd_rn(__fadd_rn(__fmul_rn(qx, x), __fmul_rn(qy, y)), __fmul_rn(qz, z));
    float dd = __fsub_rn(__fadd_rn(qa, sbn), __fmul_rn(2.0f, dot));
    unsigned u = __float_as_uint(dd);
    u ^= (0x80000000u | (unsigned)((int)u >> 31));  // order-preserving transform
    keys[j] = u;
  }
#pragma unroll 1
  for (int r = 0; r < KK; r++) {
    unsigned bv = keys[0];
    int bj = 0;
#pragma unroll
    for (int j = 1; j < 64; j++) {
      if (keys[j] < bv) { bv = keys[j]; bj = j; }
    }
    unsigned long long gk = ((unsigned long long)bv << 32) | (unsigned)(bj * 64 + lane);
#pragma unroll
    for (int m = 1; m < 64; m <<= 1) {
      unsigned long long o = __shfl_xor(gk, m);
      gk = o < gk ? o : gk;
    }
    int n = (int)(unsigned)gk;
    if (lane == 0) { knn[q * KK + r] = n; selk[wid][r] = n; }
    if (lane == (n & 63)) {
      int jj = n >> 6;
#pragma unroll
      for (int j = 0; j < 64; j++)
        if (j == jj) keys[j] = 0xFFFFFFFFu;
    }
  }
  // std partial sums over diff = grouped - anchor (24*67 values per query)
  double s1 = 0.0, s2 = 0.0;
#pragma unroll 1
  for (int i = 0; i < 26; i++) {
    int e = lane + 64 * i;
    if (e < KK * 67) {
      int k = e / 67, c = e - k * 67;
      int n = selk[wid][k];
      float g, mm;
      if (c < CC) {
        g = points[(b * NN + n) * CC + c];
        mm = newp[q * CC + c];
      } else {
        int cc = c - CC;
        g = cc == 0 ? lx[n] : (cc == 1 ? ly[n] : lz[n]);
        mm = nxyz[q * 3 + cc];
      }
      float v = __fsub_rn(g, mm);
      s1 += (double)v;
      s2 += (double)v * (double)v;
    }
  }
#pragma unroll
  for (int m = 1; m < 64; m <<= 1) {
    s1 += __shfl_xor(s1, m);
    s2 += __shfl_xor(s2, m);
  }
  if (lane == 0) { spart[q * 2 + 0] = s1; spart[q * 2 + 1] = s2; }
}

// ---------------------------------------------------------------------------
// finalize std per batch -> stdp = std + 1e-5
// ---------------------------------------------------------------------------
__global__ __launch_bounds__(256) void k_stdfin(
    const double* __restrict__ spart, float* __restrict__ stdp) {
  __shared__ double a1[256], a2[256];
  const int b = blockIdx.x, t = threadIdx.x;
  double s1 = 0.0, s2 = 0.0;
  for (int i = t; i < SS; i += 256) {
    s1 += spart[(b * SS + i) * 2 + 0];
    s2 += spart[(b * SS + i) * 2 + 1];
  }
  a1[t] = s1; a2[t] = s2;
  __syncthreads();
  for (int w = 128; w > 0; w >>= 1) {
    if (t < w) { a1[t] += a1[t + w]; a2[t] += a2[t + w]; }
    __syncthreads();
  }
  if (t == 0) {
    const double n = (double)SS * KK * 67;
    double m = a1[0] / n;
    double var = (a2[0] - a1[0] * m) / (n - 1.0);
    if (var < 0.0) var = 0.0;
    float stdf = (float)sqrt(var);
    stdp[b] = stdf + 1e-5f;
  }
}

// ---------------------------------------------------------------------------
// fused PreExtraction: one block per (b,s) sample.
// Builds normalized feats A[131][K] in LDS, then transfer conv + 2 residual
// blocks + max-pool over K. Thread tile: 4 co x 3 k. Weights read from global
// (L2-resident f32, [ci][co] layout, float4 per thread).
// ---------------------------------------------------------------------------
template <int NCI>
DEVINL void conv_acc(const float (*IN)[25], const float* __restrict__ wt,
                     int co0, int k0, float acc[4][3]) {
#pragma unroll
  for (int i = 0; i < 4; i++)
#pragma unroll
    for (int j = 0; j < 3; j++) acc[i][j] = 0.f;
#pragma unroll 4
  for (int ci = 0; ci < NCI; ci++) {
    float4 w = *(const float4*)(wt + ci * 128 + co0);
    float a0 = IN[ci][k0 + 0];
    float a1 = IN[ci][k0 + 1];
    float a2 = IN[ci][k0 + 2];
    acc[0][0] = fmaf(w.x, a0, acc[0][0]); acc[0][1] = fmaf(w.x, a1, acc[0][1]); acc[0][2] = fmaf(w.x, a2, acc[0][2]);
    acc[1][0] = fmaf(w.y, a0, acc[1][0]); acc[1][1] = fmaf(w.y, a1, acc[1][1]); acc[1][2] = fmaf(w.y, a2, acc[1][2]);
    acc[2][0] = fmaf(w.z, a0, acc[2][0]); acc[2][1] = fmaf(w.z, a1, acc[2][1]); acc[2][2] = fmaf(w.z, a2, acc[2][2]);
    acc[3][0] = fmaf(w.w, a0, acc[3][0]); acc[3][1] = fmaf(w.w, a1, acc[3][1]); acc[3][2] = fmaf(w.w, a2, acc[3][2]);
  }
}

__global__ __launch_bounds__(256, 4) void k_pre(
    const float* __restrict__ points,
    const float* __restrict__ alpha, const float* __restrict__ beta,
    const float* __restrict__ xs, const float* __restrict__ ys, const float* __restrict__ zs,
    const float* __restrict__ nxyz, const float* __restrict__ newp,
    const float* __restrict__ stdp, const int* __restrict__ knn,
    const float* __restrict__ wt_tr, const float* __restrict__ wt_sq,
    const float* __restrict__ bnsb, float* __restrict__ pre_out) {
  __shared__ float A[INCH][25];
  __shared__ float X[128][25];
  __shared__ float Y[128][25];
  __shared__ int kn[KK];
  __shared__ float npl[CC], nxl[3], al[67], bt[67];
  __shared__ float stds;
  const int q = blockIdx.x, b = q >> 10, t = threadIdx.x;
  if (t < KK) kn[t] = knn[q * KK + t];
  if (t < 67) { al[t] = alpha[t]; bt[t] = beta[t]; }
  if (t < CC) npl[t] = newp[q * CC + t];
  if (t < 3) nxl[t] = nxyz[q * 3 + t];
  if (t == 0) stds = stdp[b];
  __syncthreads();
  // build normalized grouped features (channels 0..66)
  for (int e = t; e < KK * 67; e += 256) {
    int k = e / 67, c = e - k * 67;
    int n = kn[k];
    float g, mm;
    if (c < CC) {
      g = points[(b * NN + n) * CC + c];
      mm = npl[c];
    } else {
      int cc = c - CC;
      g = cc == 0 ? xs[b * NN + n] : (cc == 1 ? ys[b * NN + n] : zs[b * NN + n]);
      mm = nxl[cc];
    }
    float v = __fsub_rn(g, mm);
    float tt = __fdiv_rn(v, stds);
    A[c][k] = __fadd_rn(__fmul_rn(al[c], tt), bt[c]);
  }
  // anchor channels 67..130 (raw new_points broadcast over k)
  for (int e = t; e < CC * KK; e += 256) {
    int c = e / KK, k = e - c * KK;
    A[67 + c][k] = npl[c];
  }
  __syncthreads();
  const int co0 = (t >> 3) << 2, k0 = (t & 7) * 3;
  float acc[4][3];
  // L0: transfer 131->128, BN+ReLU -> X
  conv_acc<131>(A, wt_tr, co0, k0, acc);
  {
    const float* bn = bnsb + 0 * 256;
#pragma unroll
    for (int i = 0; i < 4; i++) {
      float sc = bn[co0 + i], bi = bn[128 + co0 + i];
#pragma unroll
      for (int j = 0; j < 3; j++)
        X[co0 + i][k0 + j] = fmaxf(fmaf(acc[i][j], sc, bi), 0.f);
    }
  }
  __syncthreads();
  // L1: res1 conv a, BN+ReLU -> Y
  conv_acc<128>(X, wt_sq + 0 * 16384, co0, k0, acc);
  {
    const float* bn = bnsb + 1 * 256;
#pragma unroll
    for (int i = 0; i < 4; i++) {
      float sc = bn[co0 + i], bi = bn[128 + co0 + i];
#pragma unroll
      for (int j = 0; j < 3; j++)
        Y[co0 + i][k0 + j] = fmaxf(fmaf(acc[i][j], sc, bi), 0.f);
    }
  }
  __syncthreads();
  // L2: res1 conv b, BN, +X, ReLU -> Z (reuse A storage)
  float (*Z)[25] = A;
  conv_acc<128>(Y, wt_sq + 1 * 16384, co0, k0, acc);
  {
    const float* bn = bnsb + 2 * 256;
#pragma unroll
    for (int i = 0; i < 4; i++) {
      float sc = bn[co0 + i], bi = bn[128 + co0 + i];
#pragma unroll
      for (int j = 0; j < 3; j++)
        Z[co0 + i][k0 + j] =
            fmaxf(fmaf(acc[i][j], sc, bi) + X[co0 + i][k0 + j], 0.f);
    }
  }
  __syncthreads();
  // L3: res2 conv a, BN+ReLU -> X
  conv_acc<128>(Z, wt_sq + 2 * 16384, co0, k0, acc);
  {
    const float* bn = bnsb + 3 * 256;
#pragma unroll
    for (int i = 0; i < 4; i++) {
      float sc = bn[co0 + i], bi = bn[128 + co0 + i];
#pragma unroll
      for (int j = 0; j < 3; j++)
        X[co0 + i][k0 + j] = fmaxf(fmaf(acc[i][j], sc, bi), 0.f);
    }
  }
  __syncthreads();
  // L4: res2 conv b, BN, +Z, ReLU, max-pool over K -> pre_out
  conv_acc<128>(X, wt_sq + 3 * 16384, co0, k0, acc);
  {
    const float* bn = bnsb + 4 * 256;
    float mx[4];
#pragma unroll
    for (int i = 0; i < 4; i++) {
      float sc = bn[co0 + i], bi = bn[128 + co0 + i];
      float v0 = fmaxf(fmaf(acc[i][0], sc, bi) + Z[co0 + i][k0 + 0], 0.f);
      float v1 = fmaxf(fmaf(acc[i][1], sc, bi) + Z[co0 + i][k0 + 1], 0.f);
      float v2 = fmaxf(fmaf(acc[i][2], sc, bi) + Z[co0 + i][k0 + 2], 0.f);
      mx[i] = fmaxf(fmaxf(v0, v1), v2);
    }
#pragma unroll
    for (int mk = 1; mk < 8; mk <<= 1) {
#pragma unroll
      for (int i = 0; i < 4; i++) mx[i] = fmaxf(mx[i], __shfl_xor(mx[i], mk));
    }
    if ((t & 7) == 0) {
      float4 o;
      o.x = mx[0]; o.y = mx[1]; o.z = mx[2]; o.w = mx[3];
      *(float4*)&pre_out[q * 128 + co0] = o;
    }
  }
}

// ---------------------------------------------------------------------------
// PosExtraction: 64 positions per block; 2 residual blocks on [128] channels;
// writes f32 output [B,128,S]. Thread tile: 4 co x 8 p.
// ---------------------------------------------------------------------------
__global__ __launch_bounds__(256, 2) void k_pos(
    const float* __restrict__ pre_out, const float* __restrict__ wt_sq,
    const float* __restrict__ bnsb, float* __restrict__ out) {
  __shared__ float X[128][68];
  __shared__ float Y[128][68];
  const int blk = blockIdx.x, t = threadIdx.x;
  const int b = blk >> 4, s0 = (blk & 15) << 6;
  for (int e = t; e < 128 * 64; e += 256) {
    int sl = e >> 7, c = e & 127;
    X[c][sl] = pre_out[(b * SS + s0 + sl) * 128 + c];
  }
  __syncthreads();
  const int co0 = (t >> 3) << 2, p0 = (t & 7) << 3;
  float acc[4][8];
  auto conv = [&](const float (*IN)[68], const float* wt) {
#pragma unroll
    for (int i = 0; i < 4; i++)
#pragma unroll
      for (int j = 0; j < 8; j++) acc[i][j] = 0.f;
#pragma unroll 2
    for (int ci = 0; ci < 128; ci++) {
      float4 w = *(const float4*)(wt + ci * 128 + co0);
      float4 r0 = *(const float4*)&IN[ci][p0];
      float4 r1 = *(const float4*)&IN[ci][p0 + 4];
      float a[8] = {r0.x, r0.y, r0.z, r0.w, r1.x, r1.y, r1.z, r1.w};
#pragma unroll
      for (int j = 0; j < 8; j++) {
        acc[0][j] = fmaf(w.x, a[j], acc[0][j]);
        acc[1][j] = fmaf(w.y, a[j], acc[1][j]);
        acc[2][j] = fmaf(w.z, a[j], acc[2][j]);
        acc[3][j] = fmaf(w.w, a[j], acc[3][j]);
      }
    }
  };
  // L5: pos res1 conv a -> Y (BN+ReLU)
  conv(X, wt_sq + 4 * 16384);
  {
    const float* bn = bnsb + 5 * 256;
#pragma unroll
    for (int i = 0; i < 4; i++) {
      float sc = bn[co0 + i], bi = bn[128 + co0 + i];
#pragma unroll
      for (int j = 0; j < 8; j++)
        Y[co0 + i][p0 + j] = fmaxf(fmaf(acc[i][j], sc, bi), 0.f);
    }
  }
  __syncthreads();
  // L6: pos res1 conv b, BN, +X, ReLU -> X (in place)
  conv(Y, wt_sq + 5 * 16384);
  {
    const float* bn = bnsb + 6 * 256;
#pragma unroll
    for (int i = 0; i < 4; i++) {
      float sc = bn[co0 + i], bi = bn[128 + co0 + i];
#pragma unroll
      for (int j = 0; j < 8; j++)
        X[co0 + i][p0 + j] =
            fmaxf(fmaf(acc[i][j], sc, bi) + X[co0 + i][p0 + j], 0.f);
    }
  }
  __syncthreads();
  // L7: pos res2 conv a -> Y (BN+ReLU)
  conv(X, wt_sq + 6 * 16384);
  {
    const float* bn = bnsb + 7 * 256;
#pragma unroll
    for (int i = 0; i < 4; i++) {
      float sc = bn[co0 + i], bi = bn[128 + co0 + i];
#pragma unroll
      for (int j = 0; j < 8; j++)
        Y[co0 + i][p0 + j] = fmaxf(fmaf(acc[i][j], sc, bi), 0.f);
    }
  }
  __syncthreads();
  // L8: pos res2 conv b, BN, +X, ReLU -> out (f32)
  conv(Y, wt_sq + 7 * 16384);
  {
    const float* bn = bnsb + 8 * 256;
#pragma unroll
    for (int i = 0; i < 4; i++) {
      float sc = bn[co0 + i], bi = bn[128 + co0 + i];
      float4 o0, o1;
      float v;
      v = fmaxf(fmaf(acc[i][0], sc, bi) + X[co0 + i][p0 + 0], 0.f); o0.x = v;
      v = fmaxf(fmaf(acc[i][1], sc, bi) + X[co0 + i][p0 + 1], 0.f); o0.y = v;
      v = fmaxf(fmaf(acc[i][2], sc, bi) + X[co0 + i][p0 + 2], 0.f); o0.z = v;
      v = fmaxf(fmaf(acc[i][3], sc, bi) + X[co0 + i][p0 + 3], 0.f); o0.w = v;
      v = fmaxf(fmaf(acc[i][4], sc, bi) + X[co0 + i][p0 + 4], 0.f); o1.x = v;
      v = fmaxf(fmaf(acc[i][5], sc, bi) + X[co0 + i][p0 + 5], 0.f); o1.y = v;
      v = fmaxf(fmaf(acc[i][6], sc, bi) + X[co0 + i][p0 + 6], 0.f); o1.z = v;
      v = fmaxf(fmaf(acc[i][7], sc, bi) + X[co0 + i][p0 + 7], 0.f); o1.w = v;
      float* op = &out[(size_t)(b * 128 + co0 + i) * SS + s0 + p0];
      *(float4*)op = o0;
      *(float4*)(op + 4) = o1;
    }
  }
}

// ---------------------------------------------------------------------------
extern "C" void kernel_launch(void* const* d_in, const int* in_sizes, int n_in,
                              void* d_out, int out_size, void* d_ws, size_t ws_size,
                              hipStream_t stream) {
  (void)in_sizes; (void)n_in; (void)out_size; (void)ws_size;
  const float* xyz    = (const float*)d_in[0];
  const float* points = (const float*)d_in[1];
  const float* alpha  = (const float*)d_in[2];
  const float* beta   = (const float*)d_in[3];
  const float* tw     = (const float*)d_in[4];
  const float* tb     = (const float*)d_in[5];
  const float* tbn    = (const float*)d_in[6];
  const float* pw1    = (const float*)d_in[7];
  const float* pb1    = (const float*)d_in[8];
  const float* pbn1   = (const float*)d_in[9];
  const float* pw2    = (const float*)d_in[10];
  const float* pb2    = (const float*)d_in[11];
  const float* pbn2   = (const float*)d_in[12];
  const float* qw1    = (const float*)d_in[13];
  const float* qb1    = (const float*)d_in[14];
  const float* qbn1   = (const float*)d_in[15];
  const float* qw2    = (const float*)d_in[16];
  const float* qb2    = (const float*)d_in[17];
  const float* qbn2   = (const float*)d_in[18];

  char* ws = (char*)d_ws;
  size_t off = 0;
  auto alloc = [&](size_t bytes) -> char* {
    char* p = ws + off;
    off += (bytes + 255) & ~(size_t)255;
    return p;
  };
  float*  xs    = (float*)alloc(BB * NN * 4);
  float*  ys    = (float*)alloc(BB * NN * 4);
  float*  zs    = (float*)alloc(BB * NN * 4);
  float*  sb    = (float*)alloc(BB * NN * 4);
  float*  wt_tr = (float*)alloc(INCH * 128 * 4);
  float*  wt_sq = (float*)alloc(8 * 16384 * 4);
  float*  bnsb  = (float*)alloc(9 * 256 * 4);
  int*    fps   = (int*)alloc(BB * SS * 4);
  float*  nxyz  = (float*)alloc(BB * SS * 3 * 4);
  float*  sa    = (float*)alloc(BB * SS * 4);
  float*  newp  = (float*)alloc(BB * SS * CC * 4);
  int*    knn   = (int*)alloc(BB * SS * KK * 4);
  double* spart = (double*)alloc(BB * SS * 2 * 8);
  float*  stdp  = (float*)alloc(256);
  float*  preo  = (float*)alloc((size_t)BB * SS * 128 * 4);
  float*  out   = (float*)d_out;

  hipLaunchKernelGGL(k_prep_xyz, dim3((BB * NN + 255) / 256), dim3(256), 0, stream,
                     xyz, xs, ys, zs, sb);
  hipLaunchKernelGGL(k_prep_w, dim3((INCH * 128 + 8 * 16384 + 9 * 128 + 255) / 256),
                     dim3(256), 0, stream,
                     tw, pw1, pw2, qw1, qw2, tb, tbn, pb1, pbn1, pb2, pbn2,
                     qb1, qbn1, qb2, qbn2, wt_tr, wt_sq, bnsb);
  hipLaunchKernelGGL(k_fps, dim3(BB), dim3(512), 0, stream,
                     xs, ys, zs, sb, points, fps, nxyz, sa, newp);
  hipLaunchKernelGGL(k_knn, dim3(BB * SS / 4), dim3(256), 0, stream,
                     xs, ys, zs, nxyz, sa, points, newp, knn, spart);
  hipLaunchKernelGGL(k_stdfin, dim3(BB), dim3(256), 0, stream, spart, stdp);
  hipLaunchKernelGGL(k_pre, dim3(BB * SS), dim3(256), 0, stream,
                     points, alpha, beta, xs, ys, zs, nxyz, newp, stdp, knn,
                     wt_tr, wt_sq, bnsb, preo);
  hipLaunchKernelGGL(k_pos, dim3(BB * SS / 64), dim3(256), 0, stream,
                     preo, wt_sq, bnsb, out);
}